// Round 5
// baseline (548.091 us; speedup 1.0000x reference)
//
#include <hip/hip_runtime.h>

// MoE MLP (B=2,T=2048,H=1024,E=8,F=4096,K=2), fp32 in/out.
// route -> group tokens by expert -> FUSED grouped GEMMs that stream fp32
// weights ONCE from HBM (convert to bf16 in-register, transpose via
// ds_write_b128 into swizzled [n][k] LDS), persistent (expert, n-panel)
// blocks with y-loop, counted-vmcnt pipeline -> weighted combine.

typedef unsigned short ushort_t;
typedef __attribute__((ext_vector_type(2))) float f32x2;
typedef __attribute__((ext_vector_type(4))) unsigned int u32x4;
typedef __attribute__((ext_vector_type(4))) unsigned short u16x4;
typedef __attribute__((ext_vector_type(4))) float f32x4;
typedef __attribute__((ext_vector_type(8))) __bf16 bf16x8;

#define NTOK 4096   // B*T
#define HD   1024
#define FD   4096
#define NE   8
#define NKTOT 8192  // NTOK * TOP_K

__device__ __forceinline__ ushort_t f2bf(float f) {
  unsigned u = __builtin_bit_cast(unsigned, f);
  u += 0x7fffu + ((u >> 16) & 1u);   // RNE
  return (ushort_t)(u >> 16);
}
__device__ __forceinline__ unsigned pk2(float a, float b) {
  unsigned r;
  asm("v_cvt_pk_bf16_f32 %0, %1, %2" : "=v"(r) : "v"(a), "v"(b));
  return r;  // lo = bf16(a), hi = bf16(b), RNE
}
__device__ __forceinline__ bf16x8 frag_ld(const void* p) {
  u32x4 v = *reinterpret_cast<const u32x4*>(p);
  return __builtin_bit_cast(bf16x8, v);
}

#define GLOAD16(g, l) __builtin_amdgcn_global_load_lds(                         \
    (const __attribute__((address_space(1))) unsigned int*)(g),                 \
    (__attribute__((address_space(3))) unsigned int*)(l), 16, 0, 0)

#define WAITLGKM() do { asm volatile("s_waitcnt lgkmcnt(0)" ::: "memory");      \
                        __builtin_amdgcn_sched_barrier(0); } while (0)
#define WAITVM8() asm volatile("s_waitcnt vmcnt(8)" ::: "memory")
#define WAITVM0() asm volatile("s_waitcnt vmcnt(0)" ::: "memory")
#define BARRIER() do { asm volatile("s_waitcnt lgkmcnt(0)" ::: "memory");       \
                       __builtin_amdgcn_s_barrier(); } while (0)

// ---------------------------------------------------------------- init
__global__ void init_k(int* counts) {
  if (threadIdx.x < NE) counts[threadIdx.x] = 0;
}

// ------------------------------------------------------- x fp32->bf16
__global__ void convx_k(const float* __restrict__ src, ushort_t* __restrict__ dst) {
  const size_t i = ((size_t)blockIdx.x * 256 + threadIdx.x) * 4;
  const f32x4 v = *reinterpret_cast<const f32x4*>(src + i);
  u16x4 o;
  o.x = f2bf(v.x); o.y = f2bf(v.y); o.z = f2bf(v.z); o.w = f2bf(v.w);
  *reinterpret_cast<u16x4*>(dst + i) = o;
}

// ---------------------------------------------------------------- router
__global__ void router_k(const float* __restrict__ x, const float* __restrict__ rw,
                         float* __restrict__ tokP, int* __restrict__ counts,
                         int* __restrict__ tk_e, int* __restrict__ tk_s,
                         float* __restrict__ tk_w) {
  const int w = threadIdx.x >> 6, l = threadIdx.x & 63;
  const int t = blockIdx.x * 4 + w;
  const float* xr = x + (size_t)t * HD;
  float acc[NE];
#pragma unroll
  for (int e = 0; e < NE; ++e) acc[e] = 0.f;
  for (int it = 0; it < HD / 64; ++it) {
    const int h = l + it * 64;
    const float xv = xr[h];
#pragma unroll
    for (int e = 0; e < NE; ++e) acc[e] = fmaf(xv, rw[e * HD + h], acc[e]);
  }
#pragma unroll
  for (int e = 0; e < NE; ++e) {
#pragma unroll
    for (int s = 32; s > 0; s >>= 1) acc[e] += __shfl_xor(acc[e], s, 64);
  }
  float m = acc[0];
#pragma unroll
  for (int e = 1; e < NE; ++e) m = fmaxf(m, acc[e]);
  float ssum = 0.f;
  float p[NE];
#pragma unroll
  for (int e = 0; e < NE; ++e) { p[e] = expf(acc[e] - m); ssum += p[e]; }
  const float inv = 1.f / ssum;
  if (l < NE) tokP[(size_t)t * NE + l] = p[l] * inv;

  if (l == 0) {
    int i0 = 0; float v0 = acc[0];
#pragma unroll
    for (int e = 1; e < NE; ++e) if (acc[e] > v0) { v0 = acc[e]; i0 = e; }
    int i1 = -1; float v1 = -3.4e38f;
#pragma unroll
    for (int e = 0; e < NE; ++e) if (e != i0 && acc[e] > v1) { v1 = acc[e]; i1 = e; }
    const float w0 = 1.f / (1.f + expf(v1 - v0));
    const int s0 = atomicAdd(&counts[i0], 1);
    const int s1 = atomicAdd(&counts[i1], 1);
    tk_e[2 * t] = i0;     tk_s[2 * t] = s0;     tk_w[2 * t] = w0;
    tk_e[2 * t + 1] = i1; tk_s[2 * t + 1] = s1; tk_w[2 * t + 1] = 1.f - w0;
  }
}

// ------------------------------------------- offsets + aux loss + tail out
__global__ void finalize_k(const float* __restrict__ tokP, const int* __restrict__ counts,
                           int* __restrict__ offsets, float* __restrict__ out_tail) {
  __shared__ float red[16][8];
  const int tid = threadIdx.x;  // 1024
  f32x4 a0 = {0.f, 0.f, 0.f, 0.f}, a1 = {0.f, 0.f, 0.f, 0.f};
#pragma unroll
  for (int k = 0; k < 4; ++k) {
    const float* p = tokP + ((size_t)tid * 4 + k) * 8;
    a0 += *reinterpret_cast<const f32x4*>(p);
    a1 += *reinterpret_cast<const f32x4*>(p + 4);
  }
#pragma unroll
  for (int s = 1; s < 64; s <<= 1) {
#pragma unroll
    for (int c = 0; c < 4; ++c) {
      a0[c] += __shfl_xor(a0[c], s, 64);
      a1[c] += __shfl_xor(a1[c], s, 64);
    }
  }
  if ((tid & 63) == 0) {
    const int wv = tid >> 6;
#pragma unroll
    for (int c = 0; c < 4; ++c) { red[wv][c] = a0[c]; red[wv][4 + c] = a1[c]; }
  }
  __syncthreads();
  if (tid == 0) {
    float P[8];
    for (int c = 0; c < 8; ++c) {
      float s = 0.f;
      for (int q = 0; q < 16; ++q) s += red[q][c];
      P[c] = s * (1.f / NTOK);
    }
    int off = 0; float aux = 0.f;
    for (int q = 0; q < NE; ++q) { offsets[q] = off; off += counts[q]; }
    for (int q = 0; q < NE; ++q) aux += ((float)counts[q] / (float)NKTOT) * P[q];
    out_tail[0] = (float)NE * aux;
    out_tail[1] = 0.f;
  }
}

// ---------------------------------------------------------------- slots
__global__ void build_slots_k(const int* __restrict__ tk_e, const int* __restrict__ tk_s,
                              const int* __restrict__ offsets, int* __restrict__ slot_token) {
  const int i = blockIdx.x * 256 + threadIdx.x;  // < NKTOT
  const int e = tk_e[i];
  slot_token[offsets[e] + tk_s[i]] = i >> 1;
}

// -------------------- fused grouped GEMM, fp32 weights streamed once -------
// Block = (n-panel of 128, expert [, k-slice]); y-loop over 256-row tiles.
// A (bf16): global_load_lds into [256r][64k] rows, 16B-chunk swizzle
//   slot' = slot ^ (row&7) via pre-swizzled global source (both-sides).
// B (fp32 W [k][n]): lane owns k=8w..8w+7, n={2l,2l+1}: 8x float2 loads ->
//   v_cvt_pk bf16 -> 2x ds_write_b128 into [128n][64k] with chunk swizzle
//   slot' = kchunk ^ ((n>>1)&7).  Reads: same proven frag_ld formula as A.
// Pipeline: 2-deep B-reg + 1-deep A prefetch, vmcnt(8) counted (=B(t+2)),
// vmcnt(0) only in the 2-step tail; raw s_barrier (no vm drain).
// G1: mid[pos][FD] = gelu(X@w1 + b1);  G2: ybuf[ks][pos][HD] = mid@w2 slice.
template <bool IS_G1>
__global__ __launch_bounds__(512, 2) void moe_fused(
    const ushort_t* __restrict__ A, const float* __restrict__ W,
    const float* __restrict__ bias,
    const int* __restrict__ counts, const int* __restrict__ offsets,
    const int* __restrict__ slot_token,
    ushort_t* __restrict__ midout, float* __restrict__ ybuf) {
  constexpr int KDF = IS_G1 ? HD : FD;   // A row stride (elems)
  constexpr int WST = IS_G1 ? FD : HD;   // W row stride (floats)
  const int e = blockIdx.y;
  const int n0 = blockIdx.x * 128;
  const int ks = IS_G1 ? 0 : blockIdx.z;
  const int KB = ks * 1024;              // k window base
  const int cnt = counts[e];
  const int off = offsets[e];
  const int nty = (cnt + 255) >> 8;

  __shared__ __align__(16) ushort_t Albuf[2][16384];  // 2 x 32KB [256r][64k]
  __shared__ __align__(16) ushort_t Blbuf[2][8192];   // 2 x 16KB [128n][64k]

  const int tid = threadIdx.x;
  const int w = tid >> 6, l = tid & 63;
  const int wr = w >> 1, wc = w & 1;     // 4 (M) x 2 (N) waves, 64x64 each

  // A staging: lane stages row (c*64+w*8+(l>>3)), slot l&7 -> global chunk
  // (l&7) ^ (row&7), row&7 == l>>3.
  const int sw = (((l & 7) ^ ((l >> 3) & 7)) << 4);

  // B source: lane owns k-rows 8w..8w+7, n cols {2l, 2l+1}
  const float* wB = W + (size_t)e * ((size_t)HD * FD) +
                    (size_t)(KB + 8 * w) * WST + n0 + 2 * l;

  f32x4 acc[4][4];

  auto stageA = [&](int t, int bb, const char* const (&ab)[4]) {
#pragma unroll
    for (int c = 0; c < 4; ++c)
      GLOAD16(ab[c] + t * 128, &Albuf[bb][(c * 64 + w * 8) * 64]);
  };
  auto issueB = [&](int t, f32x2 (&R)[8]) {
    const float* p = wB + (size_t)(t * 64) * WST;
#pragma unroll
    for (int i = 0; i < 8; ++i)
      R[i] = *reinterpret_cast<const f32x2*>(p + (size_t)i * WST);
  };
  auto writeB = [&](int dstb, const f32x2 (&R)[8]) {
    // rows n=2l and n=2l+1, k-chunk w, swizzled slot = w ^ ((n>>1)&7) = w^(l&7)
    ushort_t* d0 = &Blbuf[dstb][(2 * l) * 64 + ((w ^ (l & 7)) << 3)];
    u32x4 v0, v1;
    v0.x = pk2(R[0].x, R[1].x); v0.y = pk2(R[2].x, R[3].x);
    v0.z = pk2(R[4].x, R[5].x); v0.w = pk2(R[6].x, R[7].x);
    v1.x = pk2(R[0].y, R[1].y); v1.y = pk2(R[2].y, R[3].y);
    v1.z = pk2(R[4].y, R[5].y); v1.w = pk2(R[6].y, R[7].y);
    *reinterpret_cast<u32x4*>(d0) = v0;
    *reinterpret_cast<u32x4*>(d0 + 64) = v1;
  };
  auto compute = [&](int bb) {
    const ushort_t* Ab = Albuf[bb];
    const ushort_t* Bb = Blbuf[bb];
    const int arow = wr * 64 + (l & 15);
    const int brow = wc * 64 + (l & 15);
    const int ax = l & 7;
    const int bx = (l >> 1) & 7;
    bf16x8 afr[4], bfr[4];
#pragma unroll
    for (int kk = 0; kk < 2; ++kk) {
      const int kc = kk * 4 + (l >> 4);   // global k-chunk (8 elems each)
#pragma unroll
      for (int mm = 0; mm < 4; ++mm)
        afr[mm] = frag_ld(&Ab[(arow + mm * 16) * 64 + ((kc ^ ax) << 3)]);
#pragma unroll
      for (int nn = 0; nn < 4; ++nn)
        bfr[nn] = frag_ld(&Bb[(brow + nn * 16) * 64 + ((kc ^ bx) << 3)]);
      WAITLGKM();
      __builtin_amdgcn_s_setprio(1);
#pragma unroll
      for (int mm = 0; mm < 4; ++mm)
#pragma unroll
        for (int nn = 0; nn < 4; ++nn)
          acc[mm][nn] = __builtin_amdgcn_mfma_f32_16x16x32_bf16(
              afr[mm], bfr[nn], acc[mm][nn], 0, 0, 0);
      __builtin_amdgcn_s_setprio(0);
    }
  };

  for (int ty = 0; ty < nty; ++ty) {
    const int pos0 = off + ty * 256;
    const int rows_rem = cnt - ty * 256;
    const char* ab[4];
#pragma unroll
    for (int c = 0; c < 4; ++c) {
      const int row = c * 64 + w * 8 + (l >> 3);
      int pos = pos0 + row; if (pos > NKTOT - 1) pos = NKTOT - 1;
      const size_t ar = IS_G1 ? (size_t)slot_token[pos] : (size_t)pos;
      ab[c] = (const char*)A + (ar * KDF + KB) * 2 + sw;
    }
#pragma unroll
    for (int mm = 0; mm < 4; ++mm)
#pragma unroll
      for (int nn = 0; nn < 4; ++nn) acc[mm][nn] = f32x4{0.f, 0.f, 0.f, 0.f};

    f32x2 br0[8], br1[8];
    // prologue: B(0)->br0 [8], A(0)->buf0 [4], B(1)->br1 [8]; wait 12 -> 8;
    // write B(0); barrier.
    issueB(0, br0);
    stageA(0, 0, ab);
    issueB(1, br1);
    WAITVM8();
    writeB(0, br0);
    BARRIER();
#pragma unroll 2
    for (int t = 0; t < 16; ++t) {
      const int bb = t & 1;
      if (t + 1 < 16) stageA(t + 1, bb ^ 1, ab);
      if (t + 2 < 16) { if (bb == 0) issueB(t + 2, br0); else issueB(t + 2, br1); }
      compute(bb);
      if (t < 14) { WAITVM8(); } else { WAITVM0(); }  // A(t+1)+B(t+1) landed
      if (t + 1 < 16) { if (bb == 0) writeB(bb ^ 1, br1); else writeB(bb ^ 1, br0); }
      BARRIER();
    }

    // epilogue: C/D col = l&15, row = 4*(l>>4) + j
    const int lr4 = (l >> 4) * 4, lc = l & 15;
#pragma unroll
    for (int nn = 0; nn < 4; ++nn) {
      const int col = n0 + wc * 64 + nn * 16 + lc;
      const float bv = IS_G1 ? bias[(size_t)e * FD + col] : 0.f;
#pragma unroll
      for (int mm = 0; mm < 4; ++mm) {
        const int rb = wr * 64 + mm * 16 + lr4;
#pragma unroll
        for (int j = 0; j < 4; ++j) {
          const int row = rb + j;
          if (row < rows_rem) {
            float v = acc[mm][nn][j] + bv;
            if (IS_G1) {
              v = 0.5f * v * (1.0f + erff(v * 0.70710678118654752f));
              midout[(size_t)(pos0 + row) * FD + col] = f2bf(v);
            } else {
              ybuf[((size_t)ks * NKTOT + pos0 + row) * HD + col] = v;
            }
          }
        }
      }
    }
  }
}

// ---------------------------------------------------------------- combine
__global__ void combine_k(const float* __restrict__ ybuf, const int* __restrict__ tk_e,
                          const int* __restrict__ tk_s, const float* __restrict__ tk_w,
                          const int* __restrict__ offsets, const float* __restrict__ b2,
                          float* __restrict__ out) {
  const int t = blockIdx.x;
  const int e0 = tk_e[2 * t], e1 = tk_e[2 * t + 1];
  const size_t p0 = (size_t)offsets[e0] + tk_s[2 * t];
  const size_t p1 = (size_t)offsets[e1] + tk_s[2 * t + 1];
  const float w0 = tk_w[2 * t], w1v = tk_w[2 * t + 1];
  const int h = threadIdx.x * 4;
  f32x4 s0 = *reinterpret_cast<const f32x4*>(b2 + (size_t)e0 * HD + h);
  f32x4 s1 = *reinterpret_cast<const f32x4*>(b2 + (size_t)e1 * HD + h);
#pragma unroll
  for (int ks = 0; ks < 4; ++ks) {
    s0 += *reinterpret_cast<const f32x4*>(ybuf + ((size_t)ks * NKTOT + p0) * HD + h);
    s1 += *reinterpret_cast<const f32x4*>(ybuf + ((size_t)ks * NKTOT + p1) * HD + h);
  }
  f32x4 o = s0 * w0 + s1 * w1v;
  *reinterpret_cast<f32x4*>(out + (size_t)t * HD + h) = o;
}

// ---------------------------------------------------------------- launch
extern "C" void kernel_launch(void* const* d_in, const int* in_sizes, int n_in,
                              void* d_out, int out_size, void* d_ws, size_t ws_size,
                              hipStream_t stream) {
  const float* x  = (const float*)d_in[0];
  const float* rw = (const float*)d_in[1];
  const float* w1 = (const float*)d_in[2];
  const float* b1 = (const float*)d_in[3];
  const float* w2 = (const float*)d_in[4];
  const float* b2 = (const float*)d_in[5];
  float* out = (float*)d_out;

  char* ws = (char*)d_ws;
  ushort_t* Xbf  = (ushort_t*)(ws + 0);            //   8,388,608
  ushort_t* midb = (ushort_t*)(ws + 8388608);      //  67,108,864  [NKTOT][F] bf16
  float*    ybuf = (float*)(ws + 75497472);        // 134,217,728  [4][NKTOT][H] f32
  char* sm = ws + 209715200;
  int*   counts  = (int*)(sm);
  int*   offsets = (int*)(sm + 64);
  float* tokP    = (float*)(sm + 128);             // [NTOK][NE]
  int*   tk_e    = (int*)(sm + 128 + 131072);
  int*   tk_s    = (int*)(sm + 128 + 131072 + 32768);
  float* tk_w    = (float*)(sm + 128 + 131072 + 65536);
  int*   slot_token = (int*)(sm + 128 + 131072 + 98304);

  init_k<<<1, 64, 0, stream>>>(counts);
  convx_k<<<4096, 256, 0, stream>>>(x, Xbf);
  router_k<<<1024, 256, 0, stream>>>(x, rw, tokP, counts, tk_e, tk_s, tk_w);
  finalize_k<<<1, 1024, 0, stream>>>(tokP, counts, offsets, out + (size_t)NTOK * HD);
  build_slots_k<<<32, 256, 0, stream>>>(tk_e, tk_s, offsets, slot_token);
  moe_fused<true><<<dim3(32, 8, 1), 512, 0, stream>>>(
      Xbf, w1, b1, counts, offsets, slot_token, midb, (float*)nullptr);
  moe_fused<false><<<dim3(8, 8, 4), 512, 0, stream>>>(
      midb, w2, b2, counts, offsets, slot_token, (ushort_t*)nullptr, ybuf);
  combine_k<<<4096, 256, 0, stream>>>(ybuf, tk_e, tk_s, tk_w, offsets, b2, out);
}

// Round 6
// 523.968 us; speedup vs baseline: 1.0460x; 1.0460x over previous
//
#include <hip/hip_runtime.h>

// MoE MLP (B=2,T=2048,H=1024,E=8,F=4096,K=2), fp32 in/out.
// route -> group tokens by expert -> FUSED grouped GEMMs streaming fp32
// weights from HBM (bf16 convert in-register), XCD-pinned experts (blocks of
// one expert share one XCD's L2 for A re-reads), 3-deep A / 2-deep B pipeline
// with counted vmcnt, LDS-repacked coalesced epilogue -> weighted combine.

typedef unsigned short ushort_t;
typedef __attribute__((ext_vector_type(2))) float f32x2;
typedef __attribute__((ext_vector_type(4))) unsigned int u32x4;
typedef __attribute__((ext_vector_type(4))) unsigned short u16x4;
typedef __attribute__((ext_vector_type(4))) float f32x4;
typedef __attribute__((ext_vector_type(8))) __bf16 bf16x8;

#define NTOK 4096   // B*T
#define HD   1024
#define FD   4096
#define NE   8
#define NKTOT 8192  // NTOK * TOP_K

__device__ __forceinline__ ushort_t f2bf(float f) {
  unsigned u = __builtin_bit_cast(unsigned, f);
  u += 0x7fffu + ((u >> 16) & 1u);   // RNE
  return (ushort_t)(u >> 16);
}
__device__ __forceinline__ unsigned pk2(float a, float b) {
  unsigned r;
  asm("v_cvt_pk_bf16_f32 %0, %1, %2" : "=v"(r) : "v"(a), "v"(b));
  return r;  // lo = bf16(a), hi = bf16(b), RNE
}
__device__ __forceinline__ bf16x8 frag_ld(const void* p) {
  u32x4 v = *reinterpret_cast<const u32x4*>(p);
  return __builtin_bit_cast(bf16x8, v);
}

#define GLOAD16(g, l) __builtin_amdgcn_global_load_lds(                         \
    (const __attribute__((address_space(1))) unsigned int*)(g),                 \
    (__attribute__((address_space(3))) unsigned int*)(l), 16, 0, 0)

#define WAITLGKM() do { asm volatile("s_waitcnt lgkmcnt(0)" ::: "memory");      \
                        __builtin_amdgcn_sched_barrier(0); } while (0)
#define WAITVM12() asm volatile("s_waitcnt vmcnt(12)" ::: "memory")
#define WAITVM0()  asm volatile("s_waitcnt vmcnt(0)" ::: "memory")
#define BARRIER() do { asm volatile("s_waitcnt lgkmcnt(0)" ::: "memory");       \
                       __builtin_amdgcn_s_barrier(); } while (0)

// ---------------------------------------------------------------- init
__global__ void init_k(int* counts) {
  if (threadIdx.x < NE) counts[threadIdx.x] = 0;
}

// ------------------------------------------------------- x fp32->bf16
__global__ void convx_k(const float* __restrict__ src, ushort_t* __restrict__ dst) {
  const size_t i = ((size_t)blockIdx.x * 256 + threadIdx.x) * 4;
  const f32x4 v = *reinterpret_cast<const f32x4*>(src + i);
  u16x4 o;
  o.x = f2bf(v.x); o.y = f2bf(v.y); o.z = f2bf(v.z); o.w = f2bf(v.w);
  *reinterpret_cast<u16x4*>(dst + i) = o;
}

// ---------------------------------------------------------------- router
__global__ void router_k(const float* __restrict__ x, const float* __restrict__ rw,
                         float* __restrict__ tokP, int* __restrict__ counts,
                         int* __restrict__ tk_e, int* __restrict__ tk_s,
                         float* __restrict__ tk_w) {
  const int w = threadIdx.x >> 6, l = threadIdx.x & 63;
  const int t = blockIdx.x * 4 + w;
  const float* xr = x + (size_t)t * HD;
  float acc[NE];
#pragma unroll
  for (int e = 0; e < NE; ++e) acc[e] = 0.f;
  for (int it = 0; it < HD / 64; ++it) {
    const int h = l + it * 64;
    const float xv = xr[h];
#pragma unroll
    for (int e = 0; e < NE; ++e) acc[e] = fmaf(xv, rw[e * HD + h], acc[e]);
  }
#pragma unroll
  for (int e = 0; e < NE; ++e) {
#pragma unroll
    for (int s = 32; s > 0; s >>= 1) acc[e] += __shfl_xor(acc[e], s, 64);
  }
  float m = acc[0];
#pragma unroll
  for (int e = 1; e < NE; ++e) m = fmaxf(m, acc[e]);
  float ssum = 0.f;
  float p[NE];
#pragma unroll
  for (int e = 0; e < NE; ++e) { p[e] = expf(acc[e] - m); ssum += p[e]; }
  const float inv = 1.f / ssum;
  if (l < NE) tokP[(size_t)t * NE + l] = p[l] * inv;

  if (l == 0) {
    int i0 = 0; float v0 = acc[0];
#pragma unroll
    for (int e = 1; e < NE; ++e) if (acc[e] > v0) { v0 = acc[e]; i0 = e; }
    int i1 = -1; float v1 = -3.4e38f;
#pragma unroll
    for (int e = 0; e < NE; ++e) if (e != i0 && acc[e] > v1) { v1 = acc[e]; i1 = e; }
    const float w0 = 1.f / (1.f + expf(v1 - v0));
    const int s0 = atomicAdd(&counts[i0], 1);
    const int s1 = atomicAdd(&counts[i1], 1);
    tk_e[2 * t] = i0;     tk_s[2 * t] = s0;     tk_w[2 * t] = w0;
    tk_e[2 * t + 1] = i1; tk_s[2 * t + 1] = s1; tk_w[2 * t + 1] = 1.f - w0;
  }
}

// ------------------------------------------- offsets + aux loss + tail out
__global__ void finalize_k(const float* __restrict__ tokP, const int* __restrict__ counts,
                           int* __restrict__ offsets, float* __restrict__ out_tail) {
  __shared__ float red[16][8];
  const int tid = threadIdx.x;  // 1024
  f32x4 a0 = {0.f, 0.f, 0.f, 0.f}, a1 = {0.f, 0.f, 0.f, 0.f};
#pragma unroll
  for (int k = 0; k < 4; ++k) {
    const float* p = tokP + ((size_t)tid * 4 + k) * 8;
    a0 += *reinterpret_cast<const f32x4*>(p);
    a1 += *reinterpret_cast<const f32x4*>(p + 4);
  }
#pragma unroll
  for (int s = 1; s < 64; s <<= 1) {
#pragma unroll
    for (int c = 0; c < 4; ++c) {
      a0[c] += __shfl_xor(a0[c], s, 64);
      a1[c] += __shfl_xor(a1[c], s, 64);
    }
  }
  if ((tid & 63) == 0) {
    const int wv = tid >> 6;
#pragma unroll
    for (int c = 0; c < 4; ++c) { red[wv][c] = a0[c]; red[wv][4 + c] = a1[c]; }
  }
  __syncthreads();
  if (tid == 0) {
    float P[8];
    for (int c = 0; c < 8; ++c) {
      float s = 0.f;
      for (int q = 0; q < 16; ++q) s += red[q][c];
      P[c] = s * (1.f / NTOK);
    }
    int off = 0; float aux = 0.f;
    for (int q = 0; q < NE; ++q) { offsets[q] = off; off += counts[q]; }
    for (int q = 0; q < NE; ++q) aux += ((float)counts[q] / (float)NKTOT) * P[q];
    out_tail[0] = (float)NE * aux;
    out_tail[1] = 0.f;
  }
}

// ---------------------------------------------------------------- slots
__global__ void build_slots_k(const int* __restrict__ tk_e, const int* __restrict__ tk_s,
                              const int* __restrict__ offsets, int* __restrict__ slot_token) {
  const int i = blockIdx.x * 256 + threadIdx.x;  // < NKTOT
  const int e = tk_e[i];
  slot_token[offsets[e] + tk_s[i]] = i >> 1;
}

// -------------------- fused grouped GEMM, fp32 weights streamed once -------
// 1D grid, expert = blockIdx.x & 7 (XCD pin: linear id%8 = XCD round-robin,
// so one expert's blocks share one XCD's L2 -> A re-reads are L2 hits).
// A (bf16): global_load_lds into [256r][64k], slot' = slot ^ (row&7) swizzle,
// 3 LDS buffers (2-step flight).  B (fp32 W [k][n]): lane owns k=8w..8w+7,
// n={2l,2l+1}: 8x f32x2 -> v_cvt_pk bf16 -> 2x ds_write_b128 into [128n][64k],
// slot' = kchunk ^ ((n>>1)&7); 2-deep reg sets.  Steady wait: vmcnt(12)
// (drains exactly A(t+1)+B(t+1)); vmcnt(0) only at tail step 14.
// G1: mid = gelu(X@w1 + b1), epilogue repacked via LDS for full-line stores.
// G2: ybuf[ks] = mid@w2 k-slice (f32 direct stores, already coalesced).
template <bool IS_G1>
__global__ __launch_bounds__(512, 2) void moe_fused(
    const ushort_t* __restrict__ A, const float* __restrict__ W,
    const float* __restrict__ bias,
    const int* __restrict__ counts, const int* __restrict__ offsets,
    const int* __restrict__ slot_token,
    ushort_t* __restrict__ midout, float* __restrict__ ybuf) {
  constexpr int KDF = IS_G1 ? HD : FD;   // A row stride (elems)
  constexpr int WST = IS_G1 ? FD : HD;   // W row stride (floats)
  const int id = blockIdx.x;
  const int e = id & 7;                  // XCD pin
  const int m = id >> 3;
  const int ks = IS_G1 ? 0 : (m & 3);
  const int np = IS_G1 ? m : (m >> 2);
  const int n0 = np * 128;
  const int KB = ks * 1024;              // k window base
  const int cnt = counts[e];
  const int off = offsets[e];
  const int nty = (cnt + 255) >> 8;

  __shared__ __align__(16) ushort_t Albuf[3][16384];  // 3 x 32KB [256r][64k]
  __shared__ __align__(16) ushort_t Blbuf[2][8192];   // 2 x 16KB [128n][64k]

  const int tid = threadIdx.x;
  const int w = tid >> 6, l = tid & 63;
  const int wr = w >> 1, wc = w & 1;     // 4 (M) x 2 (N) waves, 64x64 each

  // A staging: lane stages row (c*64+w*8+(l>>3)), slot l&7 -> global chunk
  // (l&7) ^ (row&7), row&7 == l>>3.
  const int sw = (((l & 7) ^ ((l >> 3) & 7)) << 4);

  // B source: lane owns k-rows 8w..8w+7, n cols {2l, 2l+1}
  const float* wB = W + (size_t)e * ((size_t)HD * FD) +
                    (size_t)(KB + 8 * w) * WST + n0 + 2 * l;

  f32x4 acc[4][4];
  const int lr4 = (l >> 4) * 4, lc = l & 15;

  // bias per nn (G1 only), hoisted out of the ty loop
  float bv[4];
#pragma unroll
  for (int nn = 0; nn < 4; ++nn)
    bv[nn] = IS_G1 ? bias[(size_t)e * FD + n0 + wc * 64 + nn * 16 + lc] : 0.f;

  auto stageA = [&](int t, int bb, const char* const (&ab)[4]) {
#pragma unroll
    for (int c = 0; c < 4; ++c)
      GLOAD16(ab[c] + t * 128, &Albuf[bb][(c * 64 + w * 8) * 64]);
  };
  auto issueB = [&](int t, f32x2 (&R)[8]) {
    const float* p = wB + (size_t)(t * 64) * WST;
#pragma unroll
    for (int i = 0; i < 8; ++i)
      R[i] = *reinterpret_cast<const f32x2*>(p + (size_t)i * WST);
  };
  auto writeB = [&](int dstb, const f32x2 (&R)[8]) {
    // rows n=2l and n=2l+1, k-chunk w, swizzled slot = w ^ ((n>>1)&7) = w^(l&7)
    ushort_t* d0 = &Blbuf[dstb][(2 * l) * 64 + ((w ^ (l & 7)) << 3)];
    u32x4 v0, v1;
    v0.x = pk2(R[0].x, R[1].x); v0.y = pk2(R[2].x, R[3].x);
    v0.z = pk2(R[4].x, R[5].x); v0.w = pk2(R[6].x, R[7].x);
    v1.x = pk2(R[0].y, R[1].y); v1.y = pk2(R[2].y, R[3].y);
    v1.z = pk2(R[4].y, R[5].y); v1.w = pk2(R[6].y, R[7].y);
    *reinterpret_cast<u32x4*>(d0) = v0;
    *reinterpret_cast<u32x4*>(d0 + 64) = v1;
  };
  auto compute = [&](int ai, int bb) {
    const ushort_t* Ab = Albuf[ai];
    const ushort_t* Bb = Blbuf[bb];
    const int arow = wr * 64 + (l & 15);
    const int brow = wc * 64 + (l & 15);
    const int ax = l & 7;
    const int bx = (l >> 1) & 7;
    bf16x8 afr[4], bfr[4];
#pragma unroll
    for (int kk = 0; kk < 2; ++kk) {
      const int kc = kk * 4 + (l >> 4);   // global k-chunk (8 elems each)
#pragma unroll
      for (int mm = 0; mm < 4; ++mm)
        afr[mm] = frag_ld(&Ab[(arow + mm * 16) * 64 + ((kc ^ ax) << 3)]);
#pragma unroll
      for (int nn = 0; nn < 4; ++nn)
        bfr[nn] = frag_ld(&Bb[(brow + nn * 16) * 64 + ((kc ^ bx) << 3)]);
      WAITLGKM();
      __builtin_amdgcn_s_setprio(1);
#pragma unroll
      for (int mm = 0; mm < 4; ++mm)
#pragma unroll
        for (int nn = 0; nn < 4; ++nn)
          acc[mm][nn] = __builtin_amdgcn_mfma_f32_16x16x32_bf16(
              afr[mm], bfr[nn], acc[mm][nn], 0, 0, 0);
      __builtin_amdgcn_s_setprio(0);
    }
  };

  for (int ty = 0; ty < nty; ++ty) {
    const int pos0 = off + ty * 256;
    const int rows_rem = cnt - ty * 256;
    const char* ab[4];
#pragma unroll
    for (int c = 0; c < 4; ++c) {
      const int row = c * 64 + w * 8 + (l >> 3);
      int pos = pos0 + row; if (pos > NKTOT - 1) pos = NKTOT - 1;
      const size_t ar = IS_G1 ? (size_t)slot_token[pos] : (size_t)pos;
      ab[c] = (const char*)A + (ar * KDF + KB) * 2 + sw;
    }
#pragma unroll
    for (int mm = 0; mm < 4; ++mm)
#pragma unroll
      for (int nn = 0; nn < 4; ++nn) acc[mm][nn] = f32x4{0.f, 0.f, 0.f, 0.f};

    f32x2 br0[8], br1[8];
    // prologue: A(0)->Al[0], B(0)->br0, A(1)->Al[1], B(1)->br1 (24 ops);
    // vmcnt(12) drains A(0)+B(0); write B(0); barrier.
    stageA(0, 0, ab);
    issueB(0, br0);
    stageA(1, 1, ab);
    issueB(1, br1);
    WAITVM12();
    writeB(0, br0);
    BARRIER();
#pragma unroll 2
    for (int t = 0; t < 14; ++t) {
      const int bb = t & 1;
      stageA(t + 2, (t + 2) % 3, ab);
      if (bb == 0) issueB(t + 2, br0); else issueB(t + 2, br1);
      compute(t % 3, bb);
      WAITVM12();                       // drains A(t+1)+B(t+1)
      if (bb == 0) writeB(1, br1); else writeB(0, br0);
      BARRIER();
    }
    // t = 14
    compute(2, 0);
    WAITVM0();                          // drains A(15)+B(15)
    writeB(1, br1);
    BARRIER();
    // t = 15
    compute(0, 1);
    BARRIER();

    // ---- epilogue: C/D col = l&15, row = 4*(l>>4) + j
    if (IS_G1) {
      // gelu+bias -> bf16 into LDS [256][128], then coalesced row flush
      ushort_t* eb = &Albuf[0][0];
#pragma unroll
      for (int nn = 0; nn < 4; ++nn) {
        const int col = wc * 64 + nn * 16 + lc;
#pragma unroll
        for (int mm = 0; mm < 4; ++mm) {
          const int rb = wr * 64 + mm * 16 + lr4;
#pragma unroll
          for (int j = 0; j < 4; ++j) {
            float v = acc[mm][nn][j] + bv[nn];
            v = 0.5f * v * (1.0f + erff(v * 0.70710678118654752f));
            eb[(rb + j) * 128 + col] = f2bf(v);
          }
        }
      }
      BARRIER();
#pragma unroll
      for (int p = 0; p < 8; ++p) {
        const int idx = p * 4096 + tid * 8;
        const int row = idx >> 7;
        const int colq = idx & 127;
        if (row < rows_rem)
          *reinterpret_cast<u32x4*>(&midout[(size_t)(pos0 + row) * FD + n0 + colq]) =
              *reinterpret_cast<const u32x4*>(&eb[idx]);
      }
      BARRIER();
    } else {
#pragma unroll
      for (int nn = 0; nn < 4; ++nn) {
        const int col = n0 + wc * 64 + nn * 16 + lc;
#pragma unroll
        for (int mm = 0; mm < 4; ++mm) {
          const int rb = wr * 64 + mm * 16 + lr4;
#pragma unroll
          for (int j = 0; j < 4; ++j) {
            const int row = rb + j;
            if (row < rows_rem)
              ybuf[((size_t)ks * NKTOT + pos0 + row) * HD + col] = acc[mm][nn][j];
          }
        }
      }
    }
  }
}

// ---------------------------------------------------------------- combine
__global__ void combine_k(const float* __restrict__ ybuf, const int* __restrict__ tk_e,
                          const int* __restrict__ tk_s, const float* __restrict__ tk_w,
                          const int* __restrict__ offsets, const float* __restrict__ b2,
                          float* __restrict__ out) {
  const int t = blockIdx.x;
  const int e0 = tk_e[2 * t], e1 = tk_e[2 * t + 1];
  const size_t p0 = (size_t)offsets[e0] + tk_s[2 * t];
  const size_t p1 = (size_t)offsets[e1] + tk_s[2 * t + 1];
  const float w0 = tk_w[2 * t], w1v = tk_w[2 * t + 1];
  const int h = threadIdx.x * 4;
  f32x4 s0 = *reinterpret_cast<const f32x4*>(b2 + (size_t)e0 * HD + h);
  f32x4 s1 = *reinterpret_cast<const f32x4*>(b2 + (size_t)e1 * HD + h);
#pragma unroll
  for (int ks = 0; ks < 4; ++ks) {
    s0 += *reinterpret_cast<const f32x4*>(ybuf + ((size_t)ks * NKTOT + p0) * HD + h);
    s1 += *reinterpret_cast<const f32x4*>(ybuf + ((size_t)ks * NKTOT + p1) * HD + h);
  }
  f32x4 o = s0 * w0 + s1 * w1v;
  *reinterpret_cast<f32x4*>(out + (size_t)t * HD + h) = o;
}

// ---------------------------------------------------------------- launch
extern "C" void kernel_launch(void* const* d_in, const int* in_sizes, int n_in,
                              void* d_out, int out_size, void* d_ws, size_t ws_size,
                              hipStream_t stream) {
  const float* x  = (const float*)d_in[0];
  const float* rw = (const float*)d_in[1];
  const float* w1 = (const float*)d_in[2];
  const float* b1 = (const float*)d_in[3];
  const float* w2 = (const float*)d_in[4];
  const float* b2 = (const float*)d_in[5];
  float* out = (float*)d_out;

  char* ws = (char*)d_ws;
  ushort_t* Xbf  = (ushort_t*)(ws + 0);            //   8,388,608
  ushort_t* midb = (ushort_t*)(ws + 8388608);      //  67,108,864  [NKTOT][F] bf16
  float*    ybuf = (float*)(ws + 75497472);        // 134,217,728  [4][NKTOT][H] f32
  char* sm = ws + 209715200;
  int*   counts  = (int*)(sm);
  int*   offsets = (int*)(sm + 64);
  float* tokP    = (float*)(sm + 128);             // [NTOK][NE]
  int*   tk_e    = (int*)(sm + 128 + 131072);
  int*   tk_s    = (int*)(sm + 128 + 131072 + 32768);
  float* tk_w    = (float*)(sm + 128 + 131072 + 65536);
  int*   slot_token = (int*)(sm + 128 + 131072 + 98304);

  init_k<<<1, 64, 0, stream>>>(counts);
  convx_k<<<4096, 256, 0, stream>>>(x, Xbf);
  router_k<<<1024, 256, 0, stream>>>(x, rw, tokP, counts, tk_e, tk_s, tk_w);
  finalize_k<<<1, 1024, 0, stream>>>(tokP, counts, offsets, out + (size_t)NTOK * HD);
  build_slots_k<<<32, 256, 0, stream>>>(tk_e, tk_s, offsets, slot_token);
  moe_fused<true><<<256, 512, 0, stream>>>(
      Xbf, w1, b1, counts, offsets, slot_token, midb, (float*)nullptr);
  moe_fused<false><<<256, 512, 0, stream>>>(
      midb, w2, b2, counts, offsets, slot_token, (ushort_t*)nullptr, ybuf);
  combine_k<<<4096, 256, 0, stream>>>(ybuf, tk_e, tk_s, tk_w, offsets, b2, out);
}

// Round 7
// 463.295 us; speedup vs baseline: 1.1830x; 1.1310x over previous
//
#include <hip/hip_runtime.h>

// MoE MLP (B=2,T=2048,H=1024,E=8,F=4096,K=2), fp32 in/out.
// route -> group tokens by expert -> fused grouped GEMMs (m97-style 128x128
// tile, 32KB LDS, 4 blocks/CU TLP; fp32 weights streamed once, bf16 convert
// in-register) -> weighted combine. G2 = split-K2 with bf16 partials.

typedef unsigned short ushort_t;
typedef __attribute__((ext_vector_type(2))) float f32x2;
typedef __attribute__((ext_vector_type(4))) unsigned int u32x4;
typedef __attribute__((ext_vector_type(4))) unsigned short u16x4;
typedef __attribute__((ext_vector_type(4))) float f32x4;
typedef __attribute__((ext_vector_type(8))) __bf16 bf16x8;

#define NTOK 4096   // B*T
#define HD   1024
#define FD   4096
#define NE   8
#define NKTOT 8192  // NTOK * TOP_K

__device__ __forceinline__ ushort_t f2bf(float f) {
  unsigned u = __builtin_bit_cast(unsigned, f);
  u += 0x7fffu + ((u >> 16) & 1u);   // RNE
  return (ushort_t)(u >> 16);
}
__device__ __forceinline__ unsigned pk2(float a, float b) {
  unsigned r;
  asm("v_cvt_pk_bf16_f32 %0, %1, %2" : "=v"(r) : "v"(a), "v"(b));
  return r;  // lo = bf16(a), hi = bf16(b), RNE
}
__device__ __forceinline__ float bf2f(ushort_t u) {
  unsigned v = ((unsigned)u) << 16;
  return __builtin_bit_cast(float, v);
}
__device__ __forceinline__ bf16x8 frag_ld(const void* p) {
  u32x4 v = *reinterpret_cast<const u32x4*>(p);
  return __builtin_bit_cast(bf16x8, v);
}

#define GLOAD16(g, l) __builtin_amdgcn_global_load_lds(                         \
    (const __attribute__((address_space(1))) unsigned int*)(g),                 \
    (__attribute__((address_space(3))) unsigned int*)(l), 16, 0, 0)

#define WAITLGKM() do { asm volatile("s_waitcnt lgkmcnt(0)" ::: "memory");      \
                        __builtin_amdgcn_sched_barrier(0); } while (0)
#define WAITVM0()  asm volatile("s_waitcnt vmcnt(0)" ::: "memory")
#define BARRIER() do { asm volatile("s_waitcnt lgkmcnt(0)" ::: "memory");       \
                       __builtin_amdgcn_s_barrier(); } while (0)

// ---------------------------------------------------------------- init
__global__ void init_k(int* counts) {
  if (threadIdx.x < NE) counts[threadIdx.x] = 0;
}

// ------------------------------------------------------- x fp32->bf16
__global__ void convx_k(const float* __restrict__ src, ushort_t* __restrict__ dst) {
  const size_t i = ((size_t)blockIdx.x * 256 + threadIdx.x) * 4;
  const f32x4 v = *reinterpret_cast<const f32x4*>(src + i);
  u16x4 o;
  o.x = f2bf(v.x); o.y = f2bf(v.y); o.z = f2bf(v.z); o.w = f2bf(v.w);
  *reinterpret_cast<u16x4*>(dst + i) = o;
}

// ---------------------------------------------------------------- router
__global__ void router_k(const float* __restrict__ x, const float* __restrict__ rw,
                         float* __restrict__ tokP, int* __restrict__ counts,
                         int* __restrict__ tk_e, int* __restrict__ tk_s,
                         float* __restrict__ tk_w) {
  const int w = threadIdx.x >> 6, l = threadIdx.x & 63;
  const int t = blockIdx.x * 4 + w;
  const float* xr = x + (size_t)t * HD;
  float acc[NE];
#pragma unroll
  for (int e = 0; e < NE; ++e) acc[e] = 0.f;
  for (int it = 0; it < HD / 64; ++it) {
    const int h = l + it * 64;
    const float xv = xr[h];
#pragma unroll
    for (int e = 0; e < NE; ++e) acc[e] = fmaf(xv, rw[e * HD + h], acc[e]);
  }
#pragma unroll
  for (int e = 0; e < NE; ++e) {
#pragma unroll
    for (int s = 32; s > 0; s >>= 1) acc[e] += __shfl_xor(acc[e], s, 64);
  }
  float m = acc[0];
#pragma unroll
  for (int e = 1; e < NE; ++e) m = fmaxf(m, acc[e]);
  float ssum = 0.f;
  float p[NE];
#pragma unroll
  for (int e = 0; e < NE; ++e) { p[e] = expf(acc[e] - m); ssum += p[e]; }
  const float inv = 1.f / ssum;
  if (l < NE) tokP[(size_t)t * NE + l] = p[l] * inv;

  if (l == 0) {
    int i0 = 0; float v0 = acc[0];
#pragma unroll
    for (int e = 1; e < NE; ++e) if (acc[e] > v0) { v0 = acc[e]; i0 = e; }
    int i1 = -1; float v1 = -3.4e38f;
#pragma unroll
    for (int e = 0; e < NE; ++e) if (e != i0 && acc[e] > v1) { v1 = acc[e]; i1 = e; }
    const float w0 = 1.f / (1.f + expf(v1 - v0));
    const int s0 = atomicAdd(&counts[i0], 1);
    const int s1 = atomicAdd(&counts[i1], 1);
    tk_e[2 * t] = i0;     tk_s[2 * t] = s0;     tk_w[2 * t] = w0;
    tk_e[2 * t + 1] = i1; tk_s[2 * t + 1] = s1; tk_w[2 * t + 1] = 1.f - w0;
  }
}

// ------------------------------------------- offsets + aux loss + tail out
__global__ void finalize_k(const float* __restrict__ tokP, const int* __restrict__ counts,
                           int* __restrict__ offsets, float* __restrict__ out_tail) {
  __shared__ float red[16][8];
  const int tid = threadIdx.x;  // 1024
  f32x4 a0 = {0.f, 0.f, 0.f, 0.f}, a1 = {0.f, 0.f, 0.f, 0.f};
#pragma unroll
  for (int k = 0; k < 4; ++k) {
    const float* p = tokP + ((size_t)tid * 4 + k) * 8;
    a0 += *reinterpret_cast<const f32x4*>(p);
    a1 += *reinterpret_cast<const f32x4*>(p + 4);
  }
#pragma unroll
  for (int s = 1; s < 64; s <<= 1) {
#pragma unroll
    for (int c = 0; c < 4; ++c) {
      a0[c] += __shfl_xor(a0[c], s, 64);
      a1[c] += __shfl_xor(a1[c], s, 64);
    }
  }
  if ((tid & 63) == 0) {
    const int wv = tid >> 6;
#pragma unroll
    for (int c = 0; c < 4; ++c) { red[wv][c] = a0[c]; red[wv][4 + c] = a1[c]; }
  }
  __syncthreads();
  if (tid == 0) {
    float P[8];
    for (int c = 0; c < 8; ++c) {
      float s = 0.f;
      for (int q = 0; q < 16; ++q) s += red[q][c];
      P[c] = s * (1.f / NTOK);
    }
    int off = 0; float aux = 0.f;
    for (int q = 0; q < NE; ++q) { offsets[q] = off; off += counts[q]; }
    for (int q = 0; q < NE; ++q) aux += ((float)counts[q] / (float)NKTOT) * P[q];
    out_tail[0] = (float)NE * aux;
    out_tail[1] = 0.f;
  }
}

// ---------------------------------------------------------------- slots
__global__ void build_slots_k(const int* __restrict__ tk_e, const int* __restrict__ tk_s,
                              const int* __restrict__ offsets, int* __restrict__ slot_token) {
  const int i = blockIdx.x * 256 + threadIdx.x;  // < NKTOT
  const int e = tk_e[i];
  slot_token[offsets[e] + tk_s[i]] = i >> 1;
}

// ------------------- fused grouped GEMM, m97 shape, 4 blocks/CU ------------
// 256 threads, tile 128x128, As/Bs single-buffered 32KB. One output tile per
// block; grid = e(8, XCD-pinned by id&7) x np x ty(10, ty-inner so same-panel
// blocks run together and share the B panel in L2).
// A (bf16): global_load_lds [128r][64k], chunk swizzle slot'=slot^(row&7).
// B (fp32 W [k][n]): lane owns n={2l,2l+1}, k=16w..16w+15: 16x f32x2 ->
//   v_cvt_pk -> 4x ds_write_b128 into [128n][64k], slot' = s ^ ((n>>1)&7)
//   (16-lane phases hit each bank twice -> conflict-free, measured r5).
// Loop: stage A+B, vmcnt(0), writeB, barrier, compute, barrier (m97 rhythm;
// 4 blocks/CU hide the drain).  G1: mid=gelu(X@w1+b1) bf16. G2: bf16 k-slice
// partials (ks=2, K-window 2048, 32 steps), summed with b2 in combine.
template <bool IS_G1>
__global__ __launch_bounds__(256, 4) void moe_fused(
    const ushort_t* __restrict__ A, const float* __restrict__ W,
    const float* __restrict__ bias,
    const int* __restrict__ counts, const int* __restrict__ offsets,
    const int* __restrict__ slot_token,
    ushort_t* __restrict__ midout, ushort_t* __restrict__ ybuf) {
  constexpr int KDF = IS_G1 ? HD : FD;   // A row stride (elems)
  constexpr int WST = IS_G1 ? FD : HD;   // W row stride (floats)
  constexpr int NSTEP = IS_G1 ? 16 : 32;
  const int id = blockIdx.x;
  const int e = id & 7;                  // XCD pin
  const int q = id >> 3;
  const int ty = q % 10;
  const int r = q / 10;
  const int np = IS_G1 ? r : (r >> 1);
  const int ks = IS_G1 ? 0 : (r & 1);
  const int n0 = np * 128;
  const int KB = ks * 2048;              // k window base (elems)
  const int cnt = counts[e];
  if (ty * 128 >= cnt) return;
  const int off = offsets[e];
  const int pos0 = off + ty * 128;
  const int rr = cnt - ty * 128;
  const int rows_rem = rr < 128 ? rr : 128;

  __shared__ __align__(16) ushort_t lds[16384];  // As = [0,8192), Bs = [8192,16384)

  const int tid = threadIdx.x;
  const int w = tid >> 6, l = tid & 63;
  const int wr = w >> 1, wc = w & 1;     // 2 (M) x 2 (N) waves, 64x64 each

  // ---- A staging addresses (pre-swizzled source, linear LDS dest)
  const int sw = (((l & 7) ^ ((l >> 3) & 7)) << 4);
  const char* ab[4];
#pragma unroll
  for (int c = 0; c < 4; ++c) {
    const int row = c * 32 + w * 8 + (l >> 3);
    int pos = pos0 + row; if (pos > NKTOT - 1) pos = NKTOT - 1;
    const size_t ar = IS_G1 ? (size_t)slot_token[pos] : (size_t)pos;
    ab[c] = (const char*)A + (ar * KDF + KB) * 2 + sw;
  }

  // ---- B source: lane owns n cols {2l, 2l+1}, k rows 16w .. 16w+15
  const float* wB = W + (size_t)e * ((size_t)HD * FD) +
                    ((size_t)KB + 16 * w) * WST + n0 + 2 * l;

  f32x4 acc[4][4] = {};

  for (int t = 0; t < NSTEP; ++t) {
    // stage A tile t
#pragma unroll
    for (int c = 0; c < 4; ++c)
      GLOAD16(ab[c] + t * 128, &lds[(c * 32 + w * 8) * 64]);
    // load B tile t (fp32)
    f32x2 R[16];
    const float* p = wB + (size_t)(t * 64) * WST;
#pragma unroll
    for (int i = 0; i < 16; ++i)
      R[i] = *reinterpret_cast<const f32x2*>(p + (size_t)i * WST);
    WAITVM0();
    // convert + transpose-write B into Bs
    {
      ushort_t* d = &lds[8192 + (2 * l) * 64];
      const int k7 = l & 7;              // swizzle key for both cols (n>>1)&7
      u32x4 v;
      v.x = pk2(R[0].x, R[1].x); v.y = pk2(R[2].x, R[3].x);
      v.z = pk2(R[4].x, R[5].x); v.w = pk2(R[6].x, R[7].x);
      *reinterpret_cast<u32x4*>(d + (((2 * w) ^ k7) << 3)) = v;
      v.x = pk2(R[8].x, R[9].x);  v.y = pk2(R[10].x, R[11].x);
      v.z = pk2(R[12].x, R[13].x); v.w = pk2(R[14].x, R[15].x);
      *reinterpret_cast<u32x4*>(d + (((2 * w + 1) ^ k7) << 3)) = v;
      ushort_t* d2 = d + 64;
      v.x = pk2(R[0].y, R[1].y); v.y = pk2(R[2].y, R[3].y);
      v.z = pk2(R[4].y, R[5].y); v.w = pk2(R[6].y, R[7].y);
      *reinterpret_cast<u32x4*>(d2 + (((2 * w) ^ k7) << 3)) = v;
      v.x = pk2(R[8].y, R[9].y);  v.y = pk2(R[10].y, R[11].y);
      v.z = pk2(R[12].y, R[13].y); v.w = pk2(R[14].y, R[15].y);
      *reinterpret_cast<u32x4*>(d2 + (((2 * w + 1) ^ k7) << 3)) = v;
    }
    BARRIER();
    // compute
    {
      const int arow = wr * 64 + (l & 15);
      const int brow = wc * 64 + (l & 15);
      const int ax = l & 7;
      const int bx = (l >> 1) & 7;
      bf16x8 afr[4], bfr[4];
#pragma unroll
      for (int kk = 0; kk < 2; ++kk) {
        const int kc = kk * 4 + (l >> 4);
#pragma unroll
        for (int mm = 0; mm < 4; ++mm)
          afr[mm] = frag_ld(&lds[(arow + mm * 16) * 64 + ((kc ^ ax) << 3)]);
#pragma unroll
        for (int nn = 0; nn < 4; ++nn)
          bfr[nn] = frag_ld(&lds[8192 + (brow + nn * 16) * 64 + ((kc ^ bx) << 3)]);
        WAITLGKM();
        __builtin_amdgcn_s_setprio(1);
#pragma unroll
        for (int mm = 0; mm < 4; ++mm)
#pragma unroll
          for (int nn = 0; nn < 4; ++nn)
            acc[mm][nn] = __builtin_amdgcn_mfma_f32_16x16x32_bf16(
                afr[mm], bfr[nn], acc[mm][nn], 0, 0, 0);
        __builtin_amdgcn_s_setprio(0);
      }
    }
    BARRIER();
  }

  // ---- epilogue: acc -> bf16 via LDS repack, coalesced 16B row stores.
  // C/D: col = l&15, row = 4*(l>>4)+j within each 16x16 frag.
  {
    const int lr4 = (l >> 4) * 4, lc = l & 15;
#pragma unroll
    for (int nn = 0; nn < 4; ++nn) {
      const int col = wc * 64 + nn * 16 + lc;
      const float bv = IS_G1 ? bias[(size_t)e * FD + n0 + col] : 0.f;
#pragma unroll
      for (int mm = 0; mm < 4; ++mm) {
        const int rb = wr * 64 + mm * 16 + lr4;
#pragma unroll
        for (int j = 0; j < 4; ++j) {
          float v = acc[mm][nn][j] + bv;
          if (IS_G1) v = 0.5f * v * (1.0f + erff(v * 0.70710678118654752f));
          lds[(rb + j) * 128 + col] = f2bf(v);
        }
      }
    }
    BARRIER();
#pragma unroll
    for (int p = 0; p < 8; ++p) {
      const int idx = p * 2048 + tid * 8;
      const int row = idx >> 7;
      const int col = idx & 127;
      if (row < rows_rem) {
        const u32x4 v = *reinterpret_cast<const u32x4*>(&lds[idx]);
        if (IS_G1)
          *reinterpret_cast<u32x4*>(&midout[(size_t)(pos0 + row) * FD + n0 + col]) = v;
        else
          *reinterpret_cast<u32x4*>(
              &ybuf[((size_t)ks * NKTOT + pos0 + row) * HD + n0 + col]) = v;
      }
    }
  }
}

// ---------------------------------------------------------------- combine
__global__ void combine_k(const ushort_t* __restrict__ ybuf, const int* __restrict__ tk_e,
                          const int* __restrict__ tk_s, const float* __restrict__ tk_w,
                          const int* __restrict__ offsets, const float* __restrict__ b2,
                          float* __restrict__ out) {
  const int t = blockIdx.x;
  const int e0 = tk_e[2 * t], e1 = tk_e[2 * t + 1];
  const size_t p0 = (size_t)offsets[e0] + tk_s[2 * t];
  const size_t p1 = (size_t)offsets[e1] + tk_s[2 * t + 1];
  const float w0 = tk_w[2 * t], w1v = tk_w[2 * t + 1];
  const int h = threadIdx.x * 4;
  f32x4 s0 = *reinterpret_cast<const f32x4*>(b2 + (size_t)e0 * HD + h);
  f32x4 s1 = *reinterpret_cast<const f32x4*>(b2 + (size_t)e1 * HD + h);
#pragma unroll
  for (int ks = 0; ks < 2; ++ks) {
    const u16x4 a = *reinterpret_cast<const u16x4*>(
        &ybuf[((size_t)ks * NKTOT + p0) * HD + h]);
    const u16x4 b = *reinterpret_cast<const u16x4*>(
        &ybuf[((size_t)ks * NKTOT + p1) * HD + h]);
    s0.x += bf2f(a.x); s0.y += bf2f(a.y); s0.z += bf2f(a.z); s0.w += bf2f(a.w);
    s1.x += bf2f(b.x); s1.y += bf2f(b.y); s1.z += bf2f(b.z); s1.w += bf2f(b.w);
  }
  f32x4 o = s0 * w0 + s1 * w1v;
  *reinterpret_cast<f32x4*>(out + (size_t)t * HD + h) = o;
}

// ---------------------------------------------------------------- launch
extern "C" void kernel_launch(void* const* d_in, const int* in_sizes, int n_in,
                              void* d_out, int out_size, void* d_ws, size_t ws_size,
                              hipStream_t stream) {
  const float* x  = (const float*)d_in[0];
  const float* rw = (const float*)d_in[1];
  const float* w1 = (const float*)d_in[2];
  const float* b1 = (const float*)d_in[3];
  const float* w2 = (const float*)d_in[4];
  const float* b2 = (const float*)d_in[5];
  float* out = (float*)d_out;

  char* ws = (char*)d_ws;
  ushort_t* Xbf  = (ushort_t*)(ws + 0);            //   8,388,608
  ushort_t* midb = (ushort_t*)(ws + 8388608);      //  67,108,864  [NKTOT][F] bf16
  ushort_t* ybuf = (ushort_t*)(ws + 75497472);     //  33,554,432  [2][NKTOT][H] bf16
  char* sm = ws + 209715200;
  int*   counts  = (int*)(sm);
  int*   offsets = (int*)(sm + 64);
  float* tokP    = (float*)(sm + 128);             // [NTOK][NE]
  int*   tk_e    = (int*)(sm + 128 + 131072);
  int*   tk_s    = (int*)(sm + 128 + 131072 + 32768);
  float* tk_w    = (float*)(sm + 128 + 131072 + 65536);
  int*   slot_token = (int*)(sm + 128 + 131072 + 98304);

  init_k<<<1, 64, 0, stream>>>(counts);
  convx_k<<<4096, 256, 0, stream>>>(x, Xbf);
  router_k<<<1024, 256, 0, stream>>>(x, rw, tokP, counts, tk_e, tk_s, tk_w);
  finalize_k<<<1, 1024, 0, stream>>>(tokP, counts, offsets, out + (size_t)NTOK * HD);
  build_slots_k<<<32, 256, 0, stream>>>(tk_e, tk_s, offsets, slot_token);
  // G1 grid: e(8) x [np(32) x ty(10)] = 2560 blocks
  moe_fused<true><<<2560, 256, 0, stream>>>(
      Xbf, w1, b1, counts, offsets, slot_token, midb, (ushort_t*)nullptr);
  // G2 grid: e(8) x [np(8) x ks(2) x ty(10)] = 1280 blocks
  moe_fused<false><<<1280, 256, 0, stream>>>(
      midb, w2, b2, counts, offsets, slot_token, (ushort_t*)nullptr, ybuf);
  combine_k<<<4096, 256, 0, stream>>>(ybuf, tk_e, tk_s, tk_w, offsets, b2, out);
}

// Round 8
// 397.758 us; speedup vs baseline: 1.3779x; 1.1648x over previous
//
#include <hip/hip_runtime.h>

// MoE MLP (B=2,T=2048,H=1024,E=8,F=4096,K=2), fp32 in/out.
// route -> group tokens by expert -> fused grouped GEMMs (256x128 tile,
// 512 thr, 2 blocks/CU, T14 async-stage: issue loads early, compute, then
// write-late with counted vmcnt; fp32 weights streamed once, bf16 convert
// in-register) -> weighted combine.  G2 = split-K2 with bf16 partials.

typedef unsigned short ushort_t;
typedef __attribute__((ext_vector_type(2))) float f32x2;
typedef __attribute__((ext_vector_type(4))) unsigned int u32x4;
typedef __attribute__((ext_vector_type(4))) unsigned short u16x4;
typedef __attribute__((ext_vector_type(4))) float f32x4;
typedef __attribute__((ext_vector_type(8))) __bf16 bf16x8;

#define NTOK 4096   // B*T
#define HD   1024
#define FD   4096
#define NE   8
#define NKTOT 8192  // NTOK * TOP_K

__device__ __forceinline__ ushort_t f2bf(float f) {
  unsigned u = __builtin_bit_cast(unsigned, f);
  u += 0x7fffu + ((u >> 16) & 1u);   // RNE
  return (ushort_t)(u >> 16);
}
__device__ __forceinline__ unsigned pk2(float a, float b) {
  unsigned r;
  asm("v_cvt_pk_bf16_f32 %0, %1, %2" : "=v"(r) : "v"(a), "v"(b));
  return r;  // lo = bf16(a), hi = bf16(b), RNE
}
__device__ __forceinline__ float bf2f(ushort_t u) {
  unsigned v = ((unsigned)u) << 16;
  return __builtin_bit_cast(float, v);
}
__device__ __forceinline__ bf16x8 frag_ld(const void* p) {
  u32x4 v = *reinterpret_cast<const u32x4*>(p);
  return __builtin_bit_cast(bf16x8, v);
}

#define GLOAD16(g, l) __builtin_amdgcn_global_load_lds(                         \
    (const __attribute__((address_space(1))) unsigned int*)(g),                 \
    (__attribute__((address_space(3))) unsigned int*)(l), 16, 0, 0)

#define WAITVM4()  asm volatile("s_waitcnt vmcnt(4)" ::: "memory")
#define WAITVM0()  asm volatile("s_waitcnt vmcnt(0)" ::: "memory")
#define BARRIER() do { asm volatile("s_waitcnt lgkmcnt(0)" ::: "memory");       \
                       __builtin_amdgcn_s_barrier(); } while (0)

// ---------------------------------------------------------------- init
__global__ void init_k(int* counts) {
  if (threadIdx.x < NE) counts[threadIdx.x] = 0;
}

// ------------------------------------------------------- x fp32->bf16
__global__ void convx_k(const float* __restrict__ src, ushort_t* __restrict__ dst) {
  const size_t i = ((size_t)blockIdx.x * 256 + threadIdx.x) * 4;
  const f32x4 v = *reinterpret_cast<const f32x4*>(src + i);
  u16x4 o;
  o.x = f2bf(v.x); o.y = f2bf(v.y); o.z = f2bf(v.z); o.w = f2bf(v.w);
  *reinterpret_cast<u16x4*>(dst + i) = o;
}

// ---------------------------------------------------------------- router
__global__ void router_k(const float* __restrict__ x, const float* __restrict__ rw,
                         float* __restrict__ tokP, int* __restrict__ counts,
                         int* __restrict__ tk_e, int* __restrict__ tk_s,
                         float* __restrict__ tk_w) {
  const int w = threadIdx.x >> 6, l = threadIdx.x & 63;
  const int t = blockIdx.x * 4 + w;
  const float* xr = x + (size_t)t * HD;
  float acc[NE];
#pragma unroll
  for (int e = 0; e < NE; ++e) acc[e] = 0.f;
  for (int it = 0; it < HD / 64; ++it) {
    const int h = l + it * 64;
    const float xv = xr[h];
#pragma unroll
    for (int e = 0; e < NE; ++e) acc[e] = fmaf(xv, rw[e * HD + h], acc[e]);
  }
#pragma unroll
  for (int e = 0; e < NE; ++e) {
#pragma unroll
    for (int s = 32; s > 0; s >>= 1) acc[e] += __shfl_xor(acc[e], s, 64);
  }
  float m = acc[0];
#pragma unroll
  for (int e = 1; e < NE; ++e) m = fmaxf(m, acc[e]);
  float ssum = 0.f;
  float p[NE];
#pragma unroll
  for (int e = 0; e < NE; ++e) { p[e] = expf(acc[e] - m); ssum += p[e]; }
  const float inv = 1.f / ssum;
  if (l < NE) tokP[(size_t)t * NE + l] = p[l] * inv;

  if (l == 0) {
    int i0 = 0; float v0 = acc[0];
#pragma unroll
    for (int e = 1; e < NE; ++e) if (acc[e] > v0) { v0 = acc[e]; i0 = e; }
    int i1 = -1; float v1 = -3.4e38f;
#pragma unroll
    for (int e = 0; e < NE; ++e) if (e != i0 && acc[e] > v1) { v1 = acc[e]; i1 = e; }
    const float w0 = 1.f / (1.f + expf(v1 - v0));
    const int s0 = atomicAdd(&counts[i0], 1);
    const int s1 = atomicAdd(&counts[i1], 1);
    tk_e[2 * t] = i0;     tk_s[2 * t] = s0;     tk_w[2 * t] = w0;
    tk_e[2 * t + 1] = i1; tk_s[2 * t + 1] = s1; tk_w[2 * t + 1] = 1.f - w0;
  }
}

// ------------------------------------------- offsets + aux loss + tail out
__global__ void finalize_k(const float* __restrict__ tokP, const int* __restrict__ counts,
                           int* __restrict__ offsets, float* __restrict__ out_tail) {
  __shared__ float red[16][8];
  const int tid = threadIdx.x;  // 1024
  f32x4 a0 = {0.f, 0.f, 0.f, 0.f}, a1 = {0.f, 0.f, 0.f, 0.f};
#pragma unroll
  for (int k = 0; k < 4; ++k) {
    const float* p = tokP + ((size_t)tid * 4 + k) * 8;
    a0 += *reinterpret_cast<const f32x4*>(p);
    a1 += *reinterpret_cast<const f32x4*>(p + 4);
  }
#pragma unroll
  for (int s = 1; s < 64; s <<= 1) {
#pragma unroll
    for (int c = 0; c < 4; ++c) {
      a0[c] += __shfl_xor(a0[c], s, 64);
      a1[c] += __shfl_xor(a1[c], s, 64);
    }
  }
  if ((tid & 63) == 0) {
    const int wv = tid >> 6;
#pragma unroll
    for (int c = 0; c < 4; ++c) { red[wv][c] = a0[c]; red[wv][4 + c] = a1[c]; }
  }
  __syncthreads();
  if (tid == 0) {
    float P[8];
    for (int c = 0; c < 8; ++c) {
      float s = 0.f;
      for (int q = 0; q < 16; ++q) s += red[q][c];
      P[c] = s * (1.f / NTOK);
    }
    int off = 0; float aux = 0.f;
    for (int q = 0; q < NE; ++q) { offsets[q] = off; off += counts[q]; }
    for (int q = 0; q < NE; ++q) aux += ((float)counts[q] / (float)NKTOT) * P[q];
    out_tail[0] = (float)NE * aux;
    out_tail[1] = 0.f;
  }
}

// ---------------------------------------------------------------- slots
__global__ void build_slots_k(const int* __restrict__ tk_e, const int* __restrict__ tk_s,
                              const int* __restrict__ offsets, int* __restrict__ slot_token) {
  const int i = blockIdx.x * 256 + threadIdx.x;  // < NKTOT
  const int e = tk_e[i];
  slot_token[offsets[e] + tk_s[i]] = i >> 1;
}

// -------- fused grouped GEMM, 256x128 tile, async-stage (T14) pipeline -----
// 512 threads = 8 waves (4M x 2N, 64x64 each).  LDS: As dbuf 2x32KB (bf16,
// [256r][64k], chunk swizzle slot^=row&7, pre-swizzled global src) + Bs 16KB
// ([128n][64k], slot^= (n>>1)&7) = 80KB -> 2 blocks/CU.
// Per step t: issue B(t+1) (8x f32x2/lane) + A(t+1) (4x gload_lds); compute(t)
// immediately (A(t)/B(t) drained collectively last step); s_barrier;
// vmcnt(4) -> cvt+writeB(t+1); vmcnt(0) -> BARRIER.  Load latency hides under
// compute; vmcnt(0) before the shared barrier makes cross-wave gload_lds safe.
// G1: mid = gelu(X@w1+b1) bf16.  G2: bf16 k-slice partials (ks=2, K=2048).
template <bool IS_G1>
__global__ __launch_bounds__(512, 4) void moe_fused(
    const ushort_t* __restrict__ A, const float* __restrict__ W,
    const float* __restrict__ bias,
    const int* __restrict__ counts, const int* __restrict__ offsets,
    const int* __restrict__ slot_token,
    ushort_t* __restrict__ midout, ushort_t* __restrict__ ybuf) {
  constexpr int KDF = IS_G1 ? HD : FD;   // A row stride (elems)
  constexpr int WST = IS_G1 ? FD : HD;   // W row stride (floats)
  constexpr int NSTEP = IS_G1 ? 16 : 32;
  const int id = blockIdx.x;
  const int e = id & 7;                  // XCD pin
  const int q = id >> 3;
  const int ty = q % 5;
  const int r = q / 5;
  const int np = IS_G1 ? r : (r >> 1);
  const int ks = IS_G1 ? 0 : (r & 1);
  const int n0 = np * 128;
  const int KB = ks * 2048;              // k window base (elems)
  const int cnt = counts[e];
  if (ty * 256 >= cnt) return;
  const int off = offsets[e];
  const int pos0 = off + ty * 256;
  const int rr = cnt - ty * 256;
  const int rows_rem = rr < 256 ? rr : 256;

  // As[2][16384] = [0,32768), Bs[8192] = [32768,40960)   (80 KB)
  __shared__ __align__(16) ushort_t lds[40960];

  const int tid = threadIdx.x;
  const int w = tid >> 6, l = tid & 63;
  const int wr = w >> 1, wc = w & 1;     // 4 (M) x 2 (N) waves, 64x64 each

  // ---- A staging (pre-swizzled source, linear LDS dest)
  const int sw = (((l & 7) ^ ((l >> 3) & 7)) << 4);
  const char* ab[4];
#pragma unroll
  for (int c = 0; c < 4; ++c) {
    const int row = c * 64 + w * 8 + (l >> 3);
    int pos = pos0 + row; if (pos > NKTOT - 1) pos = NKTOT - 1;
    const size_t ar = IS_G1 ? (size_t)slot_token[pos] : (size_t)pos;
    ab[c] = (const char*)A + (ar * KDF + KB) * 2 + sw;
  }

  // ---- B source: lane owns n cols {2l, 2l+1}, k rows 8w .. 8w+7
  const float* wB = W + (size_t)e * ((size_t)HD * FD) +
                    ((size_t)KB + 8 * w) * WST + n0 + 2 * l;

  f32x4 acc[4][4] = {};
  f32x2 R[8];

  auto stageA = [&](int tt) {
    const int bb = tt & 1;
#pragma unroll
    for (int c = 0; c < 4; ++c)
      GLOAD16(ab[c] + tt * 128, &lds[bb * 16384 + (c * 64 + w * 8) * 64]);
  };
  auto issueB = [&](int tt) {
    const float* p = wB + (size_t)tt * 64 * WST;
#pragma unroll
    for (int i = 0; i < 8; ++i)
      R[i] = *reinterpret_cast<const f32x2*>(p + (size_t)i * WST);
  };
  auto writeB = [&]() {
    // rows n=2l, 2l+1; chunk w at swizzled slot w ^ ((n>>1)&7) = w ^ (l&7)
    ushort_t* d = &lds[32768 + (2 * l) * 64 + ((w ^ (l & 7)) << 3)];
    u32x4 v;
    v.x = pk2(R[0].x, R[1].x); v.y = pk2(R[2].x, R[3].x);
    v.z = pk2(R[4].x, R[5].x); v.w = pk2(R[6].x, R[7].x);
    *reinterpret_cast<u32x4*>(d) = v;
    v.x = pk2(R[0].y, R[1].y); v.y = pk2(R[2].y, R[3].y);
    v.z = pk2(R[4].y, R[5].y); v.w = pk2(R[6].y, R[7].y);
    *reinterpret_cast<u32x4*>(d + 64) = v;
  };
  auto compute = [&](int tt) {
    const ushort_t* Ab = &lds[(tt & 1) * 16384];
    const ushort_t* Bb = &lds[32768];
    const int arow = wr * 64 + (l & 15);
    const int brow = wc * 64 + (l & 15);
    const int ax = l & 7;
    const int bx = (l >> 1) & 7;
    __builtin_amdgcn_s_setprio(1);
#pragma unroll
    for (int kk = 0; kk < 2; ++kk) {
      const int kc = kk * 4 + (l >> 4);
      bf16x8 afr[4];
#pragma unroll
      for (int mm = 0; mm < 4; ++mm)
        afr[mm] = frag_ld(&Ab[(arow + mm * 16) * 64 + ((kc ^ ax) << 3)]);
#pragma unroll
      for (int nn = 0; nn < 4; ++nn) {
        const bf16x8 bfr = frag_ld(&Bb[(brow + nn * 16) * 64 + ((kc ^ bx) << 3)]);
#pragma unroll
        for (int mm = 0; mm < 4; ++mm)
          acc[mm][nn] = __builtin_amdgcn_mfma_f32_16x16x32_bf16(
              afr[mm], bfr, acc[mm][nn], 0, 0, 0);
      }
    }
    __builtin_amdgcn_s_setprio(0);
  };

  // ---- prologue: B(0)+A(0); drain B; write; drain A; barrier.
  issueB(0);
  stageA(0);
  WAITVM4();
  writeB();
  WAITVM0();
  BARRIER();

  // ---- main loop: issue-early / write-late
  for (int t = 0; t < NSTEP - 1; ++t) {
    issueB(t + 1);
    stageA(t + 1);
    __builtin_amdgcn_sched_barrier(0);   // keep issues ahead of compute
    compute(t);
    __builtin_amdgcn_s_barrier();        // all waves done reading Bs
    WAITVM4();                           // B(t+1) landed (issued first)
    writeB();
    WAITVM0();                           // this wave's A(t+1) landed
    BARRIER();                           // collectively: As/Bs(t+1) ready
  }
  compute(NSTEP - 1);
  __builtin_amdgcn_s_barrier();          // all compute done before repack

  // ---- epilogue: acc -> bf16 via LDS repack, coalesced 16B row stores.
  // C/D: col = l&15, row = 4*(l>>4)+j within each 16x16 frag.
  {
    const int lr4 = (l >> 4) * 4, lc = l & 15;
#pragma unroll
    for (int nn = 0; nn < 4; ++nn) {
      const int col = wc * 64 + nn * 16 + lc;
      const float bv = IS_G1 ? bias[(size_t)e * FD + n0 + col] : 0.f;
#pragma unroll
      for (int mm = 0; mm < 4; ++mm) {
        const int rb = wr * 64 + mm * 16 + lr4;
#pragma unroll
        for (int j = 0; j < 4; ++j) {
          float v = acc[mm][nn][j] + bv;
          if (IS_G1) v = 0.5f * v * (1.0f + erff(v * 0.70710678118654752f));
          lds[(rb + j) * 128 + col] = f2bf(v);
        }
      }
    }
    BARRIER();
#pragma unroll
    for (int p = 0; p < 8; ++p) {
      const int idx = p * 4096 + tid * 8;
      const int row = idx >> 7;
      const int col = idx & 127;
      if (row < rows_rem) {
        const u32x4 v = *reinterpret_cast<const u32x4*>(&lds[idx]);
        if (IS_G1)
          *reinterpret_cast<u32x4*>(&midout[(size_t)(pos0 + row) * FD + n0 + col]) = v;
        else
          *reinterpret_cast<u32x4*>(
              &ybuf[((size_t)ks * NKTOT + pos0 + row) * HD + n0 + col]) = v;
      }
    }
  }
}

// ---------------------------------------------------------------- combine
__global__ void combine_k(const ushort_t* __restrict__ ybuf, const int* __restrict__ tk_e,
                          const int* __restrict__ tk_s, const float* __restrict__ tk_w,
                          const int* __restrict__ offsets, const float* __restrict__ b2,
                          float* __restrict__ out) {
  const int t = blockIdx.x;
  const int e0 = tk_e[2 * t], e1 = tk_e[2 * t + 1];
  const size_t p0 = (size_t)offsets[e0] + tk_s[2 * t];
  const size_t p1 = (size_t)offsets[e1] + tk_s[2 * t + 1];
  const float w0 = tk_w[2 * t], w1v = tk_w[2 * t + 1];
  const int h = threadIdx.x * 4;
  f32x4 s0 = *reinterpret_cast<const f32x4*>(b2 + (size_t)e0 * HD + h);
  f32x4 s1 = *reinterpret_cast<const f32x4*>(b2 + (size_t)e1 * HD + h);
#pragma unroll
  for (int ks = 0; ks < 2; ++ks) {
    const u16x4 a = *reinterpret_cast<const u16x4*>(
        &ybuf[((size_t)ks * NKTOT + p0) * HD + h]);
    const u16x4 b = *reinterpret_cast<const u16x4*>(
        &ybuf[((size_t)ks * NKTOT + p1) * HD + h]);
    s0.x += bf2f(a.x); s0.y += bf2f(a.y); s0.z += bf2f(a.z); s0.w += bf2f(a.w);
    s1.x += bf2f(b.x); s1.y += bf2f(b.y); s1.z += bf2f(b.z); s1.w += bf2f(b.w);
  }
  f32x4 o = s0 * w0 + s1 * w1v;
  *reinterpret_cast<f32x4*>(out + (size_t)t * HD + h) = o;
}

// ---------------------------------------------------------------- launch
extern "C" void kernel_launch(void* const* d_in, const int* in_sizes, int n_in,
                              void* d_out, int out_size, void* d_ws, size_t ws_size,
                              hipStream_t stream) {
  const float* x  = (const float*)d_in[0];
  const float* rw = (const float*)d_in[1];
  const float* w1 = (const float*)d_in[2];
  const float* b1 = (const float*)d_in[3];
  const float* w2 = (const float*)d_in[4];
  const float* b2 = (const float*)d_in[5];
  float* out = (float*)d_out;

  char* ws = (char*)d_ws;
  ushort_t* Xbf  = (ushort_t*)(ws + 0);            //   8,388,608
  ushort_t* midb = (ushort_t*)(ws + 8388608);      //  67,108,864  [NKTOT][F] bf16
  ushort_t* ybuf = (ushort_t*)(ws + 75497472);     //  33,554,432  [2][NKTOT][H] bf16
  char* sm = ws + 209715200;
  int*   counts  = (int*)(sm);
  int*   offsets = (int*)(sm + 64);
  float* tokP    = (float*)(sm + 128);             // [NTOK][NE]
  int*   tk_e    = (int*)(sm + 128 + 131072);
  int*   tk_s    = (int*)(sm + 128 + 131072 + 32768);
  float* tk_w    = (float*)(sm + 128 + 131072 + 65536);
  int*   slot_token = (int*)(sm + 128 + 131072 + 98304);

  init_k<<<1, 64, 0, stream>>>(counts);
  convx_k<<<4096, 256, 0, stream>>>(x, Xbf);
  router_k<<<1024, 256, 0, stream>>>(x, rw, tokP, counts, tk_e, tk_s, tk_w);
  finalize_k<<<1, 1024, 0, stream>>>(tokP, counts, offsets, out + (size_t)NTOK * HD);
  build_slots_k<<<32, 256, 0, stream>>>(tk_e, tk_s, offsets, slot_token);
  // G1 grid: e(8) x [np(32) x ty(5)] = 1280 blocks
  moe_fused<true><<<1280, 512, 0, stream>>>(
      Xbf, w1, b1, counts, offsets, slot_token, midb, (ushort_t*)nullptr);
  // G2 grid: e(8) x [np(8) x ks(2) x ty(5)] = 640 blocks
  moe_fused<false><<<640, 512, 0, stream>>>(
      midb, w2, b2, counts, offsets, slot_token, (ushort_t*)nullptr, ybuf);
  combine_k<<<4096, 256, 0, stream>>>(ybuf, tk_e, tk_s, tk_w, offsets, b2, out);
}